// Round 23
// baseline (168.989 us; speedup 1.0000x reference)
//
#include <hip/hip_runtime.h>
#include <hip/hip_bf16.h>

// Problem constants
#define NN 64
#define BB 256
#define DD 1792
#define KK 35
#define PP 10
#define DQ 448          // D / 4 (float4s per row)
#define GR 8            // rows per group
#define NGRP 28         // 16-lane groups per 448-thread team
#define NT_THREADS 896  // 2 teams x 7 waves

typedef float fx4 __attribute__((ext_vector_type(4)));

// PROVEN (R2-R8): 4-step row_shr DPP chain, bound_ctrl:0.
// Leaves the 16-lane-group sum in lane 15 of each group.
__device__ __forceinline__ float group16_sum_dpp(float x) {
    asm("v_add_f32_dpp %0, %0, %0 row_shr:1 row_mask:0xf bank_mask:0xf bound_ctrl:0" : "+v"(x));
    asm("v_add_f32_dpp %0, %0, %0 row_shr:2 row_mask:0xf bank_mask:0xf bound_ctrl:0" : "+v"(x));
    asm("v_add_f32_dpp %0, %0, %0 row_shr:4 row_mask:0xf bank_mask:0xf bound_ctrl:0" : "+v"(x));
    asm("v_add_f32_dpp %0, %0, %0 row_shr:8 row_mask:0xf bank_mask:0xf bound_ctrl:0" : "+v"(x));
    return x;
}

// ---------------------------------------------------------------------------
// K1: Gf = gamma * W_net; sG[p] = sum(Gf[p]); zc[p] = dot(beta,Wnet[p]) + b_net[p]
// ---------------------------------------------------------------------------
__global__ void prep_gf(const float* __restrict__ gamma, const float* __restrict__ beta,
                        const float* __restrict__ Wnet, const float* __restrict__ bnet,
                        float* __restrict__ GF, float* __restrict__ SG, float* __restrict__ ZC) {
    const int p = blockIdx.x;
    const int tid = threadIdx.x;
    float sg = 0.f, sb = 0.f;
#pragma unroll
    for (int j = 0; j < 7; ++j) {
        int d = j * 256 + tid;
        float wv = Wnet[p * DD + d];
        float g = gamma[d] * wv;
        GF[p * DD + d] = g;
        sg += g;
        sb += beta[d] * wv;
    }
#pragma unroll
    for (int off = 32; off > 0; off >>= 1) {
        sg += __shfl_xor(sg, off);
        sb += __shfl_xor(sb, off);
    }
    __shared__ float rs[4][2];
    if ((tid & 63) == 0) { rs[tid >> 6][0] = sg; rs[tid >> 6][1] = sb; }
    __syncthreads();
    if (tid == 0) {
        float a = 0.f, c = 0.f;
#pragma unroll
        for (int w = 0; w < 4; ++w) { a += rs[w][0]; c += rs[w][1]; }
        SG[p] = a;
        ZC[p] = c + bnet[p];
    }
}

// ---------------------------------------------------------------------------
// K2: bank[b][r] = dot(task[b], Wtok[r]) + btok[r]; ptok[b][d] likewise.
// ---------------------------------------------------------------------------
__global__ void prep_bank(const float* __restrict__ task,
                          const float* __restrict__ Wtok, const float* __restrict__ btok,
                          const float* __restrict__ Wptok, const float* __restrict__ bptok,
                          float* __restrict__ bank, float* __restrict__ ptok) {
    __shared__ float ti[32 * KK];
    const int tid = threadIdx.x;
    const int b0 = blockIdx.y * 32;
    for (int i = tid; i < 32 * KK; i += 256) ti[i] = task[b0 * KK + i];

    const int r = blockIdx.x * 256 + tid;
    const bool isbank = (r < PP * DD);
    const int rr = isbank ? r : (r - PP * DD);
    const float* __restrict__ W = isbank ? Wtok : Wptok;
    const float bias = isbank ? btok[r] : bptok[rr];

    float w[KK];
#pragma unroll
    for (int k = 0; k < KK; ++k) w[k] = W[rr * KK + k];

    __syncthreads();
#pragma unroll 1
    for (int bb = 0; bb < 32; ++bb) {
        float acc = bias;
#pragma unroll
        for (int k = 0; k < KK; ++k) acc = fmaf(ti[bb * KK + k], w[k], acc);
        const int b = b0 + bb;
        if (isbank) bank[b * (PP * DD) + r] = acc;
        else        ptok[b * DD + rr]       = acc;
    }
}

// ---------------------------------------------------------------------------
// K3 (fused_pipe2): ONE 896-thread block per b = TWO wave-aligned teams of 7
// waves. Team t owns rows t*32..t*32+31 as 4 pipelined groups of 8 (R18's
// proven schedule) on team-private red/wlds. Shared barriers keep teams in
// phase; each SIMD now carries 3.5 waves -> dependent-chain and turnaround
// stalls are hidden by cross-team overlap. NT stores; raw lgkm barriers.
// ---------------------------------------------------------------------------
__global__ __launch_bounds__(NT_THREADS, 1) void fused_pipe2(
    const float* __restrict__ X, const float* __restrict__ BANK,
    const float* __restrict__ PTOK, const float* __restrict__ GF,
    const float* __restrict__ SG, const float* __restrict__ ZC,
    float* __restrict__ OUT) {
    const int tid  = threadIdx.x;
    const int team = (tid >= 448) ? 1 : 0;
    const int ttid = tid - team * 448;
    const int b    = blockIdx.x;
    const int nbase = team * 32;            // team's first row

    const float4* __restrict__ X4 = (const float4*)X;
    const float4* __restrict__ B4 = (const float4*)BANK;
    const float4* __restrict__ G4 = (const float4*)GF;
    const float4* __restrict__ P4 = (const float4*)PTOK;
    fx4* __restrict__ OO = (fx4*)OUT;

    __shared__ float red[2][2][GR][NGRP][12];   // 43008 B  [team][buf]
    __shared__ float wlds[2][2][GR][PP];        //  1280 B  [team][buf]

    // ---- persistent state: loaded once for the whole block ----
    const float4 ptk = P4[(size_t)b * DQ + ttid];
    float4 gf[PP];
#pragma unroll
    for (int p = 0; p < PP; ++p) gf[p] = G4[(size_t)p * DQ + ttid];
    float4 bk[PP];
#pragma unroll
    for (int p = 0; p < PP; ++p) bk[p] = B4[((size_t)b * PP + p) * DQ + ttid];

    const bool writer = ((ttid & 15) == 15);
    const int g16 = ttid >> 4;

    float4 x0[GR], x1[GR], x2[GR];

#define BURST(XN, GN)                                                              \
    {                                                                              \
        _Pragma("unroll")                                                          \
        for (int r = 0; r < GR; ++r)                                               \
            XN[r] = X4[((size_t)(nbase + (GN) * GR + r) * BB + b) * DQ + ttid];    \
        __builtin_amdgcn_sched_barrier(0);                                         \
    }

#define BARRIER_RAW()                                                              \
    asm volatile("s_waitcnt lgkmcnt(0)" ::: "memory");                             \
    __builtin_amdgcn_sched_barrier(0);                                             \
    __builtin_amdgcn_s_barrier();                                                  \
    __builtin_amdgcn_sched_barrier(0);

#define PHASE1(XC, RB)                                                             \
    {                                                                              \
        _Pragma("unroll")                                                          \
        for (int r = 0; r < GR; ++r) {                                             \
            float4 t;                                                              \
            t.x = XC[r].x + ptk.x; t.y = XC[r].y + ptk.y;                          \
            t.z = XC[r].z + ptk.z; t.w = XC[r].w + ptk.w;                          \
            float s1 = t.x + t.y + t.z + t.w;                                      \
            float s2 = t.x * t.x;                                                  \
            s2 = fmaf(t.y, t.y, s2); s2 = fmaf(t.z, t.z, s2);                      \
            s2 = fmaf(t.w, t.w, s2);                                               \
            float a[PP];                                                           \
            _Pragma("unroll")                                                      \
            for (int p = 0; p < PP; ++p) {                                         \
                float v = t.x * gf[p].x;                                           \
                v = fmaf(t.y, gf[p].y, v);                                         \
                v = fmaf(t.z, gf[p].z, v);                                         \
                v = fmaf(t.w, gf[p].w, v);                                         \
                a[p] = v;                                                          \
            }                                                                      \
            s1 = group16_sum_dpp(s1);                                              \
            s2 = group16_sum_dpp(s2);                                              \
            _Pragma("unroll")                                                      \
            for (int p = 0; p < PP; ++p) a[p] = group16_sum_dpp(a[p]);             \
            if (writer) {                                                          \
                float4* dst = (float4*)&red[team][RB][r][g16][0];                  \
                dst[0] = make_float4(s1, s2, a[0], a[1]);                          \
                dst[1] = make_float4(a[2], a[3], a[4], a[5]);                      \
                dst[2] = make_float4(a[6], a[7], a[8], a[9]);                      \
            }                                                                      \
        }                                                                          \
    }

#define FINALIZE(RB)                                                               \
    if (ttid < GR * 16) {                                                          \
        const int row = ttid >> 4;                                                 \
        const int v = ttid & 15;                                                   \
        float f = 0.f;                                                             \
        if (v < 12) {                                                              \
            _Pragma("unroll")                                                      \
            for (int q = 0; q < NGRP; ++q) f += red[team][RB][row][q][v];          \
        }                                                                          \
        const int bse = (ttid & 63) & ~15;                                         \
        const float mu = __shfl(f, bse)     * (1.0f / (float)DD);                  \
        const float ms = __shfl(f, bse + 1) * (1.0f / (float)DD);                  \
        const float istd = rsqrtf(ms - mu * mu + 1e-5f);                           \
        if (v >= 2 && v < 12) {                                                    \
            const int p = v - 2;                                                   \
            const float z = istd * (f - mu * SG[p]) + ZC[p];                       \
            wlds[team][RB][row][p] = 1.0f / (1.0f + __expf(-z));                   \
        }                                                                          \
    }

#define PHASE2(XC, WB, GN)                                                         \
    {                                                                              \
        _Pragma("unroll")                                                          \
        for (int r = 0; r < GR; ++r) {                                             \
            float4 acc = XC[r];                                                    \
            _Pragma("unroll")                                                      \
            for (int p = 0; p < PP; ++p) {                                         \
                const float wv = wlds[team][WB][r][p];                             \
                acc.x = fmaf(wv, bk[p].x, acc.x);                                  \
                acc.y = fmaf(wv, bk[p].y, acc.y);                                  \
                acc.z = fmaf(wv, bk[p].z, acc.z);                                  \
                acc.w = fmaf(wv, bk[p].w, acc.w);                                  \
            }                                                                      \
            fx4 av; av.x = acc.x; av.y = acc.y; av.z = acc.z; av.w = acc.w;        \
            __builtin_nontemporal_store(av,                                        \
                &OO[((size_t)(nbase + (GN) * GR + r) * BB + b) * DQ + ttid]);      \
        }                                                                          \
    }

    // ---- prologue ----
    BURST(x0, 0)

    // g0
    BURST(x1, 1) PHASE1(x0, 0) BARRIER_RAW() FINALIZE(0)
    // g1
    BURST(x2, 2) PHASE1(x1, 1) BARRIER_RAW() FINALIZE(1) PHASE2(x0, 0, 0)
    // g2
    BURST(x0, 3) PHASE1(x2, 0) BARRIER_RAW() FINALIZE(0) PHASE2(x1, 1, 1)
    // g3
    PHASE1(x0, 1) BARRIER_RAW() FINALIZE(1) PHASE2(x2, 0, 2)
    // epilogue
    BARRIER_RAW() PHASE2(x0, 1, 3)

#undef PHASE2
#undef FINALIZE
#undef PHASE1
#undef BARRIER_RAW
#undef BURST
}

// ---------------------------------------------------------------------------
extern "C" void kernel_launch(void* const* d_in, const int* in_sizes, int n_in,
                              void* d_out, int out_size, void* d_ws, size_t ws_size,
                              hipStream_t stream) {
    const float* X     = (const float*)d_in[0];
    const float* task  = (const float*)d_in[1];
    const float* Wtok  = (const float*)d_in[2];
    const float* btok  = (const float*)d_in[3];
    const float* Wptok = (const float*)d_in[4];
    const float* bptok = (const float*)d_in[5];
    const float* gamma = (const float*)d_in[6];
    const float* beta  = (const float*)d_in[7];
    const float* Wnet  = (const float*)d_in[8];
    const float* bnet  = (const float*)d_in[9];
    float* out = (float*)d_out;

    float* ws = (float*)d_ws;
    float* bank = ws;                                  // B*P*D = 4,587,520
    float* ptok = bank + (size_t)BB * PP * DD;         // B*D   =   458,752
    float* GF   = ptok + (size_t)BB * DD;              // P*D   =    17,920
    float* SG   = GF + PP * DD;                        // P
    float* ZC   = SG + PP;                             // P

    prep_gf<<<PP, 256, 0, stream>>>(gamma, beta, Wnet, bnet, GF, SG, ZC);
    prep_bank<<<dim3(77, 8), 256, 0, stream>>>(task, Wtok, btok, Wptok, bptok, bank, ptok);
    fused_pipe2<<<BB, NT_THREADS, 0, stream>>>(X, bank, ptok, GF, SG, ZC, out);
}

// Round 24
// 78.323 us; speedup vs baseline: 2.1576x; 2.1576x over previous
//
#include <hip/hip_runtime.h>
#include <hip/hip_bf16.h>

// Problem constants
#define NN 64
#define BB 256
#define DD 1792
#define KK 35
#define PP 10
#define DQ 448          // D / 4 (float4s per row)
#define GR 4            // rows per group (per team)
#define NGRP 28         // 16-lane groups per 448-thread team
#define NTH 896         // 2 teams x 7 waves

typedef float fx4 __attribute__((ext_vector_type(4)));

// PROVEN (R2-R8): 4-step row_shr DPP chain, bound_ctrl:0.
// Leaves the 16-lane-group sum in lane 15 of each group.
__device__ __forceinline__ float group16_sum_dpp(float x) {
    asm("v_add_f32_dpp %0, %0, %0 row_shr:1 row_mask:0xf bank_mask:0xf bound_ctrl:0" : "+v"(x));
    asm("v_add_f32_dpp %0, %0, %0 row_shr:2 row_mask:0xf bank_mask:0xf bound_ctrl:0" : "+v"(x));
    asm("v_add_f32_dpp %0, %0, %0 row_shr:4 row_mask:0xf bank_mask:0xf bound_ctrl:0" : "+v"(x));
    asm("v_add_f32_dpp %0, %0, %0 row_shr:8 row_mask:0xf bank_mask:0xf bound_ctrl:0" : "+v"(x));
    return x;
}

// ---------------------------------------------------------------------------
// K1: Gf = gamma * W_net; sG[p] = sum(Gf[p]); zc[p] = dot(beta,Wnet[p]) + b_net[p]
// ---------------------------------------------------------------------------
__global__ void prep_gf(const float* __restrict__ gamma, const float* __restrict__ beta,
                        const float* __restrict__ Wnet, const float* __restrict__ bnet,
                        float* __restrict__ GF, float* __restrict__ SG, float* __restrict__ ZC) {
    const int p = blockIdx.x;
    const int tid = threadIdx.x;
    float sg = 0.f, sb = 0.f;
#pragma unroll
    for (int j = 0; j < 7; ++j) {
        int d = j * 256 + tid;
        float wv = Wnet[p * DD + d];
        float g = gamma[d] * wv;
        GF[p * DD + d] = g;
        sg += g;
        sb += beta[d] * wv;
    }
#pragma unroll
    for (int off = 32; off > 0; off >>= 1) {
        sg += __shfl_xor(sg, off);
        sb += __shfl_xor(sb, off);
    }
    __shared__ float rs[4][2];
    if ((tid & 63) == 0) { rs[tid >> 6][0] = sg; rs[tid >> 6][1] = sb; }
    __syncthreads();
    if (tid == 0) {
        float a = 0.f, c = 0.f;
#pragma unroll
        for (int w = 0; w < 4; ++w) { a += rs[w][0]; c += rs[w][1]; }
        SG[p] = a;
        ZC[p] = c + bnet[p];
    }
}

// ---------------------------------------------------------------------------
// K2: bank[b][r] = dot(task[b], Wtok[r]) + btok[r]; ptok[b][d] likewise.
// ---------------------------------------------------------------------------
__global__ void prep_bank(const float* __restrict__ task,
                          const float* __restrict__ Wtok, const float* __restrict__ btok,
                          const float* __restrict__ Wptok, const float* __restrict__ bptok,
                          float* __restrict__ bank, float* __restrict__ ptok) {
    __shared__ float ti[32 * KK];
    const int tid = threadIdx.x;
    const int b0 = blockIdx.y * 32;
    for (int i = tid; i < 32 * KK; i += 256) ti[i] = task[b0 * KK + i];

    const int r = blockIdx.x * 256 + tid;
    const bool isbank = (r < PP * DD);
    const int rr = isbank ? r : (r - PP * DD);
    const float* __restrict__ W = isbank ? Wtok : Wptok;
    const float bias = isbank ? btok[r] : bptok[rr];

    float w[KK];
#pragma unroll
    for (int k = 0; k < KK; ++k) w[k] = W[rr * KK + k];

    __syncthreads();
#pragma unroll 1
    for (int bb = 0; bb < 32; ++bb) {
        float acc = bias;
#pragma unroll
        for (int k = 0; k < KK; ++k) acc = fmaf(ti[bb * KK + k], w[k], acc);
        const int b = b0 + bb;
        if (isbank) bank[b * (PP * DD) + r] = acc;
        else        ptok[b * DD + rr]       = acc;
    }
}

// ---------------------------------------------------------------------------
// K3 (fused_lds2): ONE 896-thread block per b = 2 wave-aligned teams of 7
// waves, 14 waves/CU GUARANTEED resident (single block). Team t owns rows
// t*32..t*32+31 as 8 groups of GR=4. X staged via global_load_lds (zero
// dest VGPRs -> no spill) double-buffered per team; counted vmcnt(8)/(4)
// (R20-proven, stores never force-drained). gf/bk/ptk persistent regs
// (~110 VGPR, capped at 128 via amdgpu_waves_per_eu(4)). Raw lgkm-only
// barriers. NT stores.
// ---------------------------------------------------------------------------
__global__ __launch_bounds__(NTH, 1) __attribute__((amdgpu_waves_per_eu(4)))
void fused_lds2(
    const float* __restrict__ X, const float* __restrict__ BANK,
    const float* __restrict__ PTOK, const float* __restrict__ GF,
    const float* __restrict__ SG, const float* __restrict__ ZC,
    float* __restrict__ OUT) {
    const int tid  = threadIdx.x;
    const int team = (tid >= 448) ? 1 : 0;
    const int ttid = tid - team * 448;
    const int lane = ttid & 63;
    const int c    = ttid >> 6;         // chunk 0..6
    const int b    = blockIdx.x;
    const int nbase = team * 32;

    const float4* __restrict__ X4 = (const float4*)X;
    const float4* __restrict__ B4 = (const float4*)BANK;
    const float4* __restrict__ G4 = (const float4*)GF;
    const float4* __restrict__ P4 = (const float4*)PTOK;
    fx4* __restrict__ OO = (fx4*)OUT;

    __shared__ float xbuf[2][2][GR][DD];    // 114688 B  [team][buf]
    __shared__ float red[2][GR][NGRP][12];  //  10752 B  [team]
    __shared__ float wlds[2][GR][PP];       //    320 B  [team]

    const size_t rstride = (size_t)BB * DQ;
    const size_t gbase = (size_t)b * DQ + c * 64 + lane;

#define STAGE(BUF, GN)                                                             \
    {                                                                              \
        _Pragma("unroll")                                                          \
        for (int r = 0; r < GR; ++r) {                                             \
            const float4* src = X4 + (size_t)(nbase + (GN) * GR + r) * rstride + gbase; \
            __builtin_amdgcn_global_load_lds(                                      \
                (const __attribute__((address_space(1))) void*)src,                \
                (__attribute__((address_space(3))) void*)&xbuf[team][BUF][r][c * 256], \
                16, 0, 0);                                                         \
        }                                                                          \
        __builtin_amdgcn_sched_barrier(0);                                         \
    }

    // ---- stage group 0 first (HBM starts flowing immediately) ----
    STAGE(0, 0)

    // ---- persistent register state ----
    const float4 ptk = P4[gbase];
    float4 gf[PP];
#pragma unroll
    for (int p = 0; p < PP; ++p) gf[p] = G4[(size_t)p * DQ + c * 64 + lane];
    float4 bk[PP];
#pragma unroll
    for (int p = 0; p < PP; ++p) bk[p] = B4[((size_t)b * PP + p) * DQ + c * 64 + lane];
    const int vv = ttid & 15;
    float sgv = 0.f, zcv = 0.f;
    if (ttid < GR * 16 && vv >= 2 && vv < 12) { sgv = SG[vv - 2]; zcv = ZC[vv - 2]; }

    const bool writer = ((lane & 15) == 15);
    const int g16 = ttid >> 4;

#pragma unroll 1
    for (int g = 0; g < 8; ++g) {
        // ---- stage next group (async, no dest regs) ----
        if (g < 7) STAGE((g + 1) & 1, g + 1)

        // ---- counted wait (per-wave): leaves stores(GR)+stage(GR) in
        //      flight; guarantees stage(g) complete. Never drains stores. ----
        if (g < 7) { asm volatile("s_waitcnt vmcnt(8)" ::: "memory"); }
        else       { asm volatile("s_waitcnt vmcnt(4)" ::: "memory"); }
        __builtin_amdgcn_sched_barrier(0);

        const int cur = g & 1;

        // ---- phase 1: from LDS + gf regs ----
#pragma unroll
        for (int r = 0; r < GR; ++r) {
            const float4 x = *(const float4*)&xbuf[team][cur][r][c * 256 + lane * 4];
            float4 t;
            t.x = x.x + ptk.x; t.y = x.y + ptk.y;
            t.z = x.z + ptk.z; t.w = x.w + ptk.w;

            float s1 = t.x + t.y + t.z + t.w;
            float s2 = t.x * t.x;
            s2 = fmaf(t.y, t.y, s2); s2 = fmaf(t.z, t.z, s2); s2 = fmaf(t.w, t.w, s2);
            float a[PP];
#pragma unroll
            for (int p = 0; p < PP; ++p) {
                float v = t.x * gf[p].x;
                v = fmaf(t.y, gf[p].y, v);
                v = fmaf(t.z, gf[p].z, v);
                v = fmaf(t.w, gf[p].w, v);
                a[p] = v;
            }
            s1 = group16_sum_dpp(s1);
            s2 = group16_sum_dpp(s2);
#pragma unroll
            for (int p = 0; p < PP; ++p) a[p] = group16_sum_dpp(a[p]);

            if (writer) {
                float4* dst = (float4*)&red[team][r][g16][0];
                dst[0] = make_float4(s1, s2, a[0], a[1]);
                dst[1] = make_float4(a[2], a[3], a[4], a[5]);
                dst[2] = make_float4(a[6], a[7], a[8], a[9]);
            }
        }

        // ---- raw barrier #1 (lgkm only) ----
        asm volatile("s_waitcnt lgkmcnt(0)" ::: "memory");
        __builtin_amdgcn_sched_barrier(0);
        __builtin_amdgcn_s_barrier();
        __builtin_amdgcn_sched_barrier(0);

        // ---- finalize GR rows per team (first 64 threads of each team) ----
        if (ttid < GR * 16) {
            const int row = ttid >> 4;
            float f = 0.f;
            if (vv < 12) {
#pragma unroll
                for (int q = 0; q < NGRP; ++q) f += red[team][row][q][vv];
            }
            const int bse = (ttid & 63) & ~15;
            const float mu = __shfl(f, bse)     * (1.0f / (float)DD);
            const float ms = __shfl(f, bse + 1) * (1.0f / (float)DD);
            const float istd = rsqrtf(ms - mu * mu + 1e-5f);
            if (vv >= 2 && vv < 12) {
                const float z = istd * (f - mu * sgv) + zcv;
                wlds[team][row][vv - 2] = 1.0f / (1.0f + __expf(-z));
            }
        }

        // ---- raw barrier #2 ----
        asm volatile("s_waitcnt lgkmcnt(0)" ::: "memory");
        __builtin_amdgcn_sched_barrier(0);
        __builtin_amdgcn_s_barrier();
        __builtin_amdgcn_sched_barrier(0);

        // ---- phase 2: out = x(LDS) + w @ bank(regs), NT stores ----
#pragma unroll
        for (int r = 0; r < GR; ++r) {
            const float4 x = *(const float4*)&xbuf[team][cur][r][c * 256 + lane * 4];
            float4 acc = x;
#pragma unroll
            for (int p = 0; p < PP; ++p) {
                const float wv = wlds[team][r][p];
                acc.x = fmaf(wv, bk[p].x, acc.x);
                acc.y = fmaf(wv, bk[p].y, acc.y);
                acc.z = fmaf(wv, bk[p].z, acc.z);
                acc.w = fmaf(wv, bk[p].w, acc.w);
            }
            fx4 av; av.x = acc.x; av.y = acc.y; av.z = acc.z; av.w = acc.w;
            __builtin_nontemporal_store(av,
                &OO[(size_t)(nbase + g * GR + r) * rstride + gbase]);
        }
    }
#undef STAGE
}

// ---------------------------------------------------------------------------
extern "C" void kernel_launch(void* const* d_in, const int* in_sizes, int n_in,
                              void* d_out, int out_size, void* d_ws, size_t ws_size,
                              hipStream_t stream) {
    const float* X     = (const float*)d_in[0];
    const float* task  = (const float*)d_in[1];
    const float* Wtok  = (const float*)d_in[2];
    const float* btok  = (const float*)d_in[3];
    const float* Wptok = (const float*)d_in[4];
    const float* bptok = (const float*)d_in[5];
    const float* gamma = (const float*)d_in[6];
    const float* beta  = (const float*)d_in[7];
    const float* Wnet  = (const float*)d_in[8];
    const float* bnet  = (const float*)d_in[9];
    float* out = (float*)d_out;

    float* ws = (float*)d_ws;
    float* bank = ws;                                  // B*P*D = 4,587,520
    float* ptok = bank + (size_t)BB * PP * DD;         // B*D   =   458,752
    float* GF   = ptok + (size_t)BB * DD;              // P*D   =    17,920
    float* SG   = GF + PP * DD;                        // P
    float* ZC   = SG + PP;                             // P

    prep_gf<<<PP, 256, 0, stream>>>(gamma, beta, Wnet, bnet, GF, SG, ZC);
    prep_bank<<<dim3(77, 8), 256, 0, stream>>>(task, Wtok, btok, Wptok, bptok, bank, ptok);
    fused_lds2<<<BB, NTH, 0, stream>>>(X, bank, ptok, GF, SG, ZC, out);
}